// Round 8
// baseline (130.461 us; speedup 1.0000x reference)
//
#include <hip/hip_runtime.h>
#include <float.h>

// VQ-VAE vector quantizer forward, MI355X — bf16 MFMA with exact 3-way split.
// x: [B=32, C=64, H=64, W=64] fp32; emb: [K=512, D=64] fp32.
// out flat (b, h*w, c): out[g*64 + c] = emb[argmin_k ||x_g - emb_k||^2][c].
//
// R8 = R7 with the staging redundancy removed:
//  - pre-kernel splits emb ONCE into 3 bf16 planes in d_ws (R7 re-split the
//    same tile 2048x chip-wide inside the hot loop) + esq.
//  - planes stored with 16-B-chunk XOR swizzle (chunk ci of row k at
//    ci^(k&7)): B-frag ds_read_b128 goes 16-way -> <=2-way bank conflict.
//  - main staging = 12 float4 L2->LDS copies/thread, zero split math.
// Numerics identical to R7 (passed): 6 product classes of the 3-way
// Veltkamp bf16 split, small->large MFMA accumulation, residual ~2^-27.
// Layouts (m89/m91/m120): A[m=lane&15][k=quad*8+j], B[n=lane&15][k=quad*8+j],
// D col=lane&15, row=quad*4+reg.

typedef __attribute__((ext_vector_type(8))) short  short8;
typedef __attribute__((ext_vector_type(4))) float  floatx4;

#define HWD 4096
#define CD  64
#define KD  512
#define PT  256    // positions per block
#define KT  128    // emb rows per LDS tile

__device__ inline unsigned short bf16_rne(float v) {
    unsigned int u = __builtin_bit_cast(unsigned int, v);
    u += 0x7fffu + ((u >> 16) & 1u);
    return (unsigned short)(u >> 16);
}
__device__ inline float bf16_val(unsigned short h) {
    return __builtin_bit_cast(float, (unsigned int)h << 16);
}
__device__ inline void split3(float v, unsigned short& h, unsigned short& m,
                              unsigned short& l) {
    h = bf16_rne(v);
    float r1 = v - bf16_val(h);     // exact in fp32
    m = bf16_rne(r1);
    float r2 = r1 - bf16_val(m);    // exact in fp32
    l = bf16_rne(r2);
}

#define MFMA(A, B, C) __builtin_amdgcn_mfma_f32_16x16x32_bf16((A), (B), (C), 0, 0, 0)

// ---- pre-kernel: split emb -> 3 swizzled bf16 planes + esq (once) ----
__global__ void vq_split_kernel(const float* __restrict__ emb,
                                unsigned short* __restrict__ wh,
                                unsigned short* __restrict__ wm,
                                unsigned short* __restrict__ wl,
                                float* __restrict__ esq) {
    const int k = blockIdx.x * 256 + threadIdx.x;   // [0,512)
    const float* er = emb + (size_t)k * CD;
    unsigned short h[CD], m[CD], l[CD];
    float s = 0.f;
    #pragma unroll
    for (int c = 0; c < CD; ++c) {
        float v = er[c];
        s = fmaf(v, v, s);
        split3(v, h[c], m[c], l[c]);
    }
    esq[k] = s;
    const int sw = k & 7;
    #pragma unroll
    for (int ci = 0; ci < 8; ++ci) {
        const int dst = k * CD + ((ci ^ sw) << 3);  // swizzled 16-B chunk
        *(ushort4*)&wh[dst]     = *(ushort4*)&h[ci * 8];
        *(ushort4*)&wh[dst + 4] = *(ushort4*)&h[ci * 8 + 4];
        *(ushort4*)&wm[dst]     = *(ushort4*)&m[ci * 8];
        *(ushort4*)&wm[dst + 4] = *(ushort4*)&m[ci * 8 + 4];
        *(ushort4*)&wl[dst]     = *(ushort4*)&l[ci * 8];
        *(ushort4*)&wl[dst + 4] = *(ushort4*)&l[ci * 8 + 4];
    }
}

__launch_bounds__(256, 2)
__global__ void vq_mfma_kernel(const float* __restrict__ x,
                               const float* __restrict__ emb,
                               const unsigned short* __restrict__ wh,
                               const unsigned short* __restrict__ wm,
                               const unsigned short* __restrict__ wl,
                               const float* __restrict__ esq_g,
                               float* __restrict__ out) {
    const int tid  = threadIdx.x;
    const int lane = tid & 63;
    const int wv   = __builtin_amdgcn_readfirstlane(tid >> 6);  // 0..3
    const int n16  = lane & 15;   // m for A, n for B, col for D
    const int quad = lane >> 4;   // k-quad for A/B, row-quad for D

    const int g0 = blockIdx.x << 8;   // 256 positions per block
    const int b  = g0 >> 12;
    const int n0 = g0 & 4095;

    __shared__ unsigned short es_h[KT * CD];   // 16384 B each, swizzled image
    __shared__ unsigned short es_m[KT * CD];
    __shared__ unsigned short es_l[KT * CD];
    __shared__ float esq_s[KD];
    __shared__ int   bk_s[PT];

    // ---- stage esq once (512 floats) ----
    esq_s[tid]       = esq_g[tid];
    esq_s[256 + tid] = esq_g[256 + tid];

    // ---- A fragments: load x, split to 3 bf16 frags (held whole kernel) ----
    short8 ah[4][2], am[4][2], al[4][2];
    {
        const float* xb = x + (size_t)b * (CD * HWD) + n0 + wv * 64 + n16;
        #pragma unroll
        for (int mt = 0; mt < 4; ++mt)
            #pragma unroll
            for (int ch = 0; ch < 2; ++ch)
                #pragma unroll
                for (int j = 0; j < 8; ++j) {
                    float v = xb[(size_t)(ch * 32 + quad * 8 + j) * HWD + mt * 16];
                    unsigned short h, m, l;
                    split3(v, h, m, l);
                    ah[mt][ch][j] = (short)h;
                    am[mt][ch][j] = (short)m;
                    al[mt][ch][j] = (short)l;
                }
    }

    float bestd[16]; int bestk[16];
    #pragma unroll
    for (int i = 0; i < 16; ++i) { bestd[i] = FLT_MAX; bestk[i] = 0; }

    for (int nt = 0; nt < KD / KT; ++nt) {
        __syncthreads();   // WAR: prior tile's readers done before restage

        // ---- stage pre-split tile: 48 KB verbatim copy (12 float4/thread);
        //      i>>2 selects plane at compile time after unroll ----
        #pragma unroll
        for (int i = 0; i < 12; ++i) {
            const int off = (((i & 3) << 8) + tid) * 8;   // ushort offset
            const unsigned short* src =
                (i < 4 ? wh : i < 8 ? wm : wl) + (size_t)nt * (KT * CD) + off;
            unsigned short* dst =
                (i < 4 ? es_h : i < 8 ? es_m : es_l) + off;
            *(float4*)dst = *(const float4*)src;
        }
        __syncthreads();   // RAW: es ready

        // ---- compute: 8 local N-tiles of 16 codes ----
        #pragma unroll 2
        for (int ln = 0; ln < 8; ++ln) {
            const int krow = ln * 16 + n16;
            const int sw   = krow & 7;
            const int p0   = krow * CD + ((quad ^ sw) << 3);        // ch0 chunk
            const int p1   = krow * CD + (((4 | quad) ^ sw) << 3);  // ch1 chunk
            short8 bh0 = *(const short8*)&es_h[p0], bh1 = *(const short8*)&es_h[p1];
            short8 bm0 = *(const short8*)&es_m[p0], bm1 = *(const short8*)&es_m[p1];
            short8 bl0 = *(const short8*)&es_l[p0], bl1 = *(const short8*)&es_l[p1];
            const int   kv = nt * KT + krow;
            const float eq = esq_s[kv];

            floatx4 acc[4];
            #pragma unroll
            for (int mt = 0; mt < 4; ++mt) acc[mt] = (floatx4){0.f, 0.f, 0.f, 0.f};

            #define STEP(AR, B0, B1)                                          \
                { _Pragma("unroll")                                           \
                  for (int mt = 0; mt < 4; ++mt) acc[mt] = MFMA(AR[mt][0], B0, acc[mt]); \
                  _Pragma("unroll")                                           \
                  for (int mt = 0; mt < 4; ++mt) acc[mt] = MFMA(AR[mt][1], B1, acc[mt]); }
            STEP(al, bh0, bh1)   // ~2^-18
            STEP(am, bm0, bm1)   // ~2^-18
            STEP(ah, bl0, bl1)   // ~2^-18
            STEP(am, bh0, bh1)   // ~2^-9
            STEP(ah, bm0, bm1)   // ~2^-9
            STEP(ah, bh0, bh1)   // O(1)
            #undef STEP

            #pragma unroll
            for (int mt = 0; mt < 4; ++mt)
                #pragma unroll
                for (int r = 0; r < 4; ++r) {
                    float d = fmaf(-2.f, acc[mt][r], eq);
                    int idx = mt * 4 + r;
                    if (d < bestd[idx]) { bestd[idx] = d; bestk[idx] = kv; }
                }
        }
    }

    // ---- cross-lane argmin over the 16 code-columns (lane bits 0..3) ----
    #pragma unroll
    for (int msk = 1; msk <= 8; msk <<= 1)
        #pragma unroll
        for (int i = 0; i < 16; ++i) {
            float od = __shfl_xor(bestd[i], msk, 64);
            int   ok = __shfl_xor(bestk[i], msk, 64);
            bool take = (od < bestd[i]) || (od == bestd[i] && ok < bestk[i]);
            if (take) { bestd[i] = od; bestk[i] = ok; }
        }
    if (n16 == 0) {
        #pragma unroll
        for (int mt = 0; mt < 4; ++mt)
            #pragma unroll
            for (int r = 0; r < 4; ++r)
                bk_s[wv * 64 + mt * 16 + quad * 4 + r] = bestk[mt * 4 + r];
    }
    __syncthreads();

    // ---- gather epilogue: wave-uniform rows, 256-B coalesced, batched ----
    const size_t ob = (size_t)g0 * CD;
    for (int it = 0; it < 16; ++it) {
        float v[4]; int pp[4];
        #pragma unroll
        for (int j = 0; j < 4; ++j) {
            int p = (it * 4 + j) * 4 + wv;
            pp[j] = p;
            v[j]  = emb[bk_s[p] * CD + lane];   // L2-hot fp32 row
        }
        #pragma unroll
        for (int j = 0; j < 4; ++j)
            out[ob + (size_t)pp[j] * CD + lane] = v[j];
    }
}

extern "C" void kernel_launch(void* const* d_in, const int* in_sizes, int n_in,
                              void* d_out, int out_size, void* d_ws, size_t ws_size,
                              hipStream_t stream) {
    const float* x   = (const float*)d_in[0];   // 32*64*64*64
    const float* emb = (const float*)d_in[1];   // 512*64
    float* out = (float*)d_out;                 // 8388608 floats

    // ws layout: esq (512 f) | wh | wm | wl (each 512*64 ushort = 64 KB)
    float*          esq = (float*)d_ws;
    unsigned short* wh  = (unsigned short*)(esq + KD);
    unsigned short* wm  = wh + KD * CD;
    unsigned short* wl  = wm + KD * CD;

    vq_split_kernel<<<2, 256, 0, stream>>>(emb, wh, wm, wl, esq);
    vq_mfma_kernel<<<512, 256, 0, stream>>>(x, emb, wh, wm, wl, esq, out);
}